// Round 2
// baseline (361.208 us; speedup 1.0000x reference)
//
#include <hip/hip_runtime.h>
#include <hip/hip_bf16.h>
#include <stdint.h>
#include <stddef.h>

typedef __bf16 bf16;
typedef bf16 bf16x8 __attribute__((ext_vector_type(8)));
typedef bf16 bf16x4 __attribute__((ext_vector_type(4)));
typedef float f32x4 __attribute__((ext_vector_type(4)));

#define N_ROWS 65536
#define EMB    1024
#define ATTD   512
#define KDIM   2048
#define BM     128
#define BK     32
#define NKB    (KDIM / BK)     // 64 K-tiles
#define NBLK   (N_ROWS / BM)   // 512

__device__ __forceinline__ void gload_lds16(const void* g, void* l) {
  __builtin_amdgcn_global_load_lds(
      (const __attribute__((address_space(1))) void*)g,
      (__attribute__((address_space(3))) void*)l, 16, 0, 0);
}

// ---------------------------------------------------------------------------
// K0: W1 [2048x512] f32 (k-major) -> W1t bf16, packed as 64 contiguous 32 KiB
// per-K-tile LDS images. Image for k-tile kb: for n in 0..511, 4 chunks of
// 8 bf16; physical chunk p at elem offset n*32 + p*8 holds logical chunk
// c = p ^ ((n>>1)&3)  (i.e. k = kb*32 + c*8 + e).  This is the 64B-row XOR
// swizzle (2-way bank aliasing = free) pre-applied in global memory so K1 can
// deposit it with linear global_load_lds bursts (rule #21).
// ---------------------------------------------------------------------------
__global__ __launch_bounds__(256) void k_prep_w1(const float* __restrict__ W1,
                                                 bf16* __restrict__ W1t) {
  __shared__ float tile[32][72];
  const int kb = blockIdx.x;   // 0..63
  const int ng = blockIdx.y;   // 0..7
  const int t  = threadIdx.x;  // 0..255
  const int n0 = ng * 64;

  // load W1 block [32 k][64 n] f32
  const int kr  = t >> 3;
  const int nc8 = (t & 7) * 8;
  const float* src = W1 + (size_t)(kb * 32 + kr) * ATTD + n0 + nc8;
  float4 v0 = *(const float4*)(src);
  float4 v1 = *(const float4*)(src + 4);
  tile[kr][nc8 + 0] = v0.x; tile[kr][nc8 + 1] = v0.y;
  tile[kr][nc8 + 2] = v0.z; tile[kr][nc8 + 3] = v0.w;
  tile[kr][nc8 + 4] = v1.x; tile[kr][nc8 + 5] = v1.y;
  tile[kr][nc8 + 6] = v1.z; tile[kr][nc8 + 7] = v1.w;
  __syncthreads();

  // write swizzled bf16 image
  const int nl = t >> 2;            // 0..63
  const int p  = t & 3;             // physical chunk
  const int n  = n0 + nl;           // global n (row index in B tile)
  const int c  = p ^ ((n >> 1) & 3);
  bf16x8 o;
  #pragma unroll
  for (int e = 0; e < 8; e++) o[e] = (bf16)tile[c * 8 + e][nl];
  *(bf16x8*)(W1t + (size_t)kb * (ATTD * BK) + (size_t)n * 32 + p * 8) = o;
}

// ---------------------------------------------------------------------------
// K1: fused GEMM + tanh-MLP score + per-block softmax stats.
// 512 blocks x 512 threads (8 waves: 2M x 4N). BM=128, BN=512(all), BK=32.
// 2-phase double-buffered pipeline: prefetch tile t+1 (A->regs from HBM,
// B->LDS via global_load_lds) while computing tile t; one barrier per iter.
// ---------------------------------------------------------------------------
__global__ __launch_bounds__(512) void k_gemm_score(
    const float* __restrict__ leaves, const float* __restrict__ anc,
    const bf16* __restrict__ W1t, const float* __restrict__ b1,
    const float* __restrict__ W2, const float* __restrict__ b2,
    float* __restrict__ scores, float* __restrict__ bmax,
    float* __restrict__ bsum) {
  __shared__ bf16 ldsA[2][BM * BK];    // 2 x 8 KiB
  __shared__ bf16 ldsB[2][ATTD * BK];  // 2 x 32 KiB

  const int t    = threadIdx.x;
  const int lane = t & 63;
  const int wave = t >> 6;
  const int l15  = lane & 15;
  const int l4   = lane >> 4;
  const int wm   = wave >> 2;  // 0..1
  const int wn   = wave & 3;   // 0..3
  const int m0   = blockIdx.x * BM;

  // A-staging coords: thread -> (row, chunk): 4 threads/row, 8 f32 each
  const int ar = t >> 2;       // 0..127
  const int ac = t & 3;        // logical chunk 0..3 (k = ac*8..ac*8+7)
  const int apc = ac ^ ((ar >> 1) & 3);           // physical chunk
  const int a_lds_off = ar * BK + apc * 8;        // elems

  const f32x4 zero4 = {0.f, 0.f, 0.f, 0.f};
  f32x4 acc[4][8];
  #pragma unroll
  for (int i = 0; i < 4; i++)
    #pragma unroll
    for (int j = 0; j < 8; j++) acc[i][j] = zero4;

  // A-fragment read offsets (elems), per mi
  int a_rd[4];
  #pragma unroll
  for (int mi = 0; mi < 4; mi++) {
    const int row = wm * 64 + mi * 16 + l15;
    a_rd[mi] = row * BK + (l4 ^ ((row >> 1) & 3)) * 8;
  }
  // B-fragment read offsets (elems), per ni
  int b_rd[8];
  #pragma unroll
  for (int ni = 0; ni < 8; ni++) {
    const int nrow = wn * 128 + ni * 16 + l15;
    b_rd[ni] = nrow * BK + (l4 ^ ((nrow >> 1) & 3)) * 8;
  }

  // ---- prologue: stage tile 0 into buffer 0 ----
  {
    const float* Abase = leaves + (size_t)m0 * EMB;  // kb=0 -> leaves, k0=0
    float4 v0 = *(const float4*)(Abase + (size_t)ar * EMB + ac * 8);
    float4 v1 = *(const float4*)(Abase + (size_t)ar * EMB + ac * 8 + 4);
    #pragma unroll
    for (int j = 0; j < 4; j++)
      gload_lds16(W1t + ((size_t)(wave * 4 + j) * 64 + lane) * 8,
                  &ldsB[0][(wave * 4 + j) * 512]);
    bf16x8 o = {(bf16)v0.x, (bf16)v0.y, (bf16)v0.z, (bf16)v0.w,
                (bf16)v1.x, (bf16)v1.y, (bf16)v1.z, (bf16)v1.w};
    *(bf16x8*)(&ldsA[0][a_lds_off]) = o;
    __syncthreads();
  }

  for (int kb = 0; kb < NKB; kb++) {
    const int cur = kb & 1, nxt = cur ^ 1;
    float4 v0, v1;
    const bool pf = (kb < NKB - 1);
    if (pf) {
      // ---- issue prefetch of tile kb+1 ----
      const int kn = kb + 1;
      const float* Abase = (kn < 32)
          ? (leaves + (size_t)m0 * EMB + (size_t)kn * BK)
          : (anc    + (size_t)m0 * EMB + (size_t)(kn - 32) * BK);
      v0 = *(const float4*)(Abase + (size_t)ar * EMB + ac * 8);
      v1 = *(const float4*)(Abase + (size_t)ar * EMB + ac * 8 + 4);
      const bf16* Bsrc = W1t + (size_t)kn * (ATTD * BK);
      #pragma unroll
      for (int j = 0; j < 4; j++)
        gload_lds16(Bsrc + ((size_t)(wave * 4 + j) * 64 + lane) * 8,
                    &ldsB[nxt][(wave * 4 + j) * 512]);
    }
    // ---- compute tile kb ----
    bf16x8 afr[4];
    #pragma unroll
    for (int mi = 0; mi < 4; mi++)
      afr[mi] = *(const bf16x8*)(&ldsA[cur][a_rd[mi]]);
    #pragma unroll
    for (int ni = 0; ni < 8; ni++) {
      bf16x8 bfr = *(const bf16x8*)(&ldsB[cur][b_rd[ni]]);
      #pragma unroll
      for (int mi = 0; mi < 4; mi++)
        acc[mi][ni] = __builtin_amdgcn_mfma_f32_16x16x32_bf16(
            afr[mi], bfr, acc[mi][ni], 0, 0, 0);
    }
    if (pf) {
      bf16x8 o = {(bf16)v0.x, (bf16)v0.y, (bf16)v0.z, (bf16)v0.w,
                  (bf16)v1.x, (bf16)v1.y, (bf16)v1.z, (bf16)v1.w};
      *(bf16x8*)(&ldsA[nxt][a_lds_off]) = o;
    }
    __syncthreads();
  }

  // ---- epilogue: score[r] = b2 + sum_col tanh(h + b1[col]) * W2[col] ----
  // acc[mi][ni][reg]: row = wm*64+mi*16+l4*4+reg, col = wn*128+ni*16+l15
  float b1c[8], w2c[8];
  #pragma unroll
  for (int ni = 0; ni < 8; ni++) {
    const int col = wn * 128 + ni * 16 + l15;
    b1c[ni] = b1[col];
    w2c[ni] = W2[col];
  }
  float* sp   = (float*)&ldsA[0][0];  // 528 floats scratch (ldsA dead)
  float* redm = sp + 512;
  float* redz = sp + 520;
  #pragma unroll
  for (int mi = 0; mi < 4; mi++) {
    #pragma unroll
    for (int r = 0; r < 4; r++) {
      float p = 0.f;
      #pragma unroll
      for (int ni = 0; ni < 8; ni++)
        p += tanhf(acc[mi][ni][r] + b1c[ni]) * w2c[ni];
      p += __shfl_xor(p, 1);
      p += __shfl_xor(p, 2);
      p += __shfl_xor(p, 4);
      p += __shfl_xor(p, 8);
      if (l15 == 0) sp[wn * 128 + wm * 64 + mi * 16 + l4 * 4 + r] = p;
    }
  }
  __syncthreads();
  float myscore = 0.f;
  if (t < BM) {
    myscore = sp[t] + sp[128 + t] + sp[256 + t] + sp[384 + t] + b2[0];
    scores[m0 + t] = myscore;
  }
  float mm = (t < BM) ? myscore : -3.0e38f;
  #pragma unroll
  for (int o = 32; o; o >>= 1) mm = fmaxf(mm, __shfl_xor(mm, o));
  if (lane == 0) redm[wave] = mm;
  __syncthreads();
  if (t == 0) {
    float g = redm[0];
    for (int i = 1; i < 8; i++) g = fmaxf(g, redm[i]);
    redm[0] = g;
  }
  __syncthreads();
  const float bM = redm[0];
  float ee = (t < BM) ? __expf(myscore - bM) : 0.f;
  #pragma unroll
  for (int o = 32; o; o >>= 1) ee += __shfl_xor(ee, o);
  if (lane == 0) redz[wave] = ee;
  __syncthreads();
  if (t == 0) {
    float z = 0.f;
    for (int i = 0; i < 8; i++) z += redz[i];
    bmax[blockIdx.x] = bM;
    bsum[blockIdx.x] = z;
  }
}

// ---------------------------------------------------------------------------
// K2: reduce 512 per-block (max, sumexp) pairs -> global M, Z
// ---------------------------------------------------------------------------
__global__ __launch_bounds__(512) void k_mz(const float* __restrict__ bmax,
                                            const float* __restrict__ bsum,
                                            float* __restrict__ MZ) {
  const int t = threadIdx.x, lane = t & 63, wave = t >> 6;
  __shared__ float rm[8], rs[8];
  const float m = bmax[t];
  float mm = m;
  #pragma unroll
  for (int o = 32; o; o >>= 1) mm = fmaxf(mm, __shfl_xor(mm, o));
  if (lane == 0) rm[wave] = mm;
  __syncthreads();
  if (t == 0) {
    float g = rm[0];
    for (int i = 1; i < 8; i++) g = fmaxf(g, rm[i]);
    rm[0] = g;
  }
  __syncthreads();
  const float M = rm[0];
  float z = bsum[t] * __expf(m - M);
  #pragma unroll
  for (int o = 32; o; o >>= 1) z += __shfl_xor(z, o);
  if (lane == 0) rs[wave] = z;
  __syncthreads();
  if (t == 0) {
    float Z = 0.f;
    for (int i = 0; i < 8; i++) Z += rs[i];
    MZ[0] = M;
    MZ[1] = Z;
  }
}

// ---------------------------------------------------------------------------
// K3: per-block partial weighted sum of ancestors: part[b][j] = sum_i w_i*anc[i][j]
// ---------------------------------------------------------------------------
__global__ __launch_bounds__(256) void k_part(const float* __restrict__ anc,
                                              const float* __restrict__ scores,
                                              const float* __restrict__ MZ,
                                              float* __restrict__ part) {
  __shared__ float w[BM];
  const int b = blockIdx.x, t = threadIdx.x;
  const float M = MZ[0];
  if (t < BM) w[t] = __expf(scores[(size_t)b * BM + t] - M);
  __syncthreads();
  float4 a = {0.f, 0.f, 0.f, 0.f};
  const float4* src = (const float4*)(anc + (size_t)b * BM * EMB) + t;
  #pragma unroll 4
  for (int i = 0; i < BM; i++) {
    float4 v = src[i * (EMB / 4)];
    const float wi = w[i];
    a.x += wi * v.x;
    a.y += wi * v.y;
    a.z += wi * v.z;
    a.w += wi * v.w;
  }
  ((float4*)(part + (size_t)b * EMB))[t] = a;
}

// ---------------------------------------------------------------------------
// K4: out[j] = (sum_b part[b][j]) / Z
// ---------------------------------------------------------------------------
__global__ __launch_bounds__(256) void k_final(const float* __restrict__ part,
                                               const float* __restrict__ MZ,
                                               float* __restrict__ out) {
  const int j = blockIdx.x * 256 + threadIdx.x;
  float s0 = 0.f, s1 = 0.f, s2 = 0.f, s3 = 0.f;
  for (int b = 0; b < NBLK; b += 4) {
    s0 += part[(size_t)(b + 0) * EMB + j];
    s1 += part[(size_t)(b + 1) * EMB + j];
    s2 += part[(size_t)(b + 2) * EMB + j];
    s3 += part[(size_t)(b + 3) * EMB + j];
  }
  out[j] = (s0 + s1 + s2 + s3) / MZ[1];
}

extern "C" void kernel_launch(void* const* d_in, const int* in_sizes, int n_in,
                              void* d_out, int out_size, void* d_ws,
                              size_t ws_size, hipStream_t stream) {
  const float* leaves = (const float*)d_in[0];
  const float* anc    = (const float*)d_in[1];
  const float* W1     = (const float*)d_in[2];
  const float* b1     = (const float*)d_in[3];
  const float* W2     = (const float*)d_in[4];
  const float* b2     = (const float*)d_in[5];
  float* out = (float*)d_out;

  char* ws = (char*)d_ws;
  bf16*  W1t    = (bf16*)ws;                                  // 2 MiB
  float* scores = (float*)(ws + (1u << 21));                  // 256 KiB
  float* bmax   = (float*)(ws + (1u << 21) + (1u << 18));     // 2 KiB
  float* bsum   = bmax + NBLK;                                // 2 KiB
  float* MZ     = bsum + NBLK;                                // 8 B
  float* part   = (float*)(ws + (1u << 21) + (1u << 19));     // 2 MiB

  k_prep_w1<<<dim3(64, 8), 256, 0, stream>>>(W1, W1t);
  k_gemm_score<<<dim3(NBLK), 512, 0, stream>>>(leaves, anc, W1t, b1, W2, b2,
                                               scores, bmax, bsum);
  k_mz<<<dim3(1), 512, 0, stream>>>(bmax, bsum, MZ);
  k_part<<<dim3(NBLK), 256, 0, stream>>>(anc, scores, MZ, part);
  k_final<<<dim3(EMB / 256), 256, 0, stream>>>(part, MZ, out);
}